// Round 1
// baseline (481.774 us; speedup 1.0000x reference)
//
#include <hip/hip_runtime.h>
#include <hip/hip_bf16.h>

#define M 8192
#define N 8192
#define K 1024
#define BM 128
#define BN 128
#define BK 64

typedef __attribute__((ext_vector_type(8))) short short8;
typedef __attribute__((ext_vector_type(4))) float f32x4;

__device__ inline short f2bf(float x){
    __hip_bfloat16 h = __float2bfloat16(x);
    short s; __builtin_memcpy(&s, &h, 2); return s;
}
__device__ inline float bf2f(short s){
    __hip_bfloat16 h; __builtin_memcpy(&h, &s, 2);
    return __bfloat162float(h);
}

__device__ inline void conv8(float4 x0, float4 x1, short8& hi, short8& lo){
    float xs[8] = {x0.x,x0.y,x0.z,x0.w,x1.x,x1.y,x1.z,x1.w};
    #pragma unroll
    for (int j=0;j<8;++j){
        short h = f2bf(xs[j]);
        float r = xs[j] - bf2f(h);
        hi[j] = h; lo[j] = f2bf(r);
    }
}

// ---------------- K0: presplit f32 -> (hi, lo) bf16 ----------------
__global__ __launch_bounds__(256) void presplit(
    const float* __restrict__ A, const float* __restrict__ B,
    short* __restrict__ Ah, short* __restrict__ Al,
    short* __restrict__ Bh, short* __restrict__ Bl)
{
    size_t c = (size_t)blockIdx.x * 256 + threadIdx.x; // chunk of 8 floats
    const float* src; short *dh, *dl; size_t off;
    const size_t perMat = (size_t)M * K / 8; // 1048576
    if (c < perMat){ src = A; dh = Ah; dl = Al; off = c * 8; }
    else           { src = B; dh = Bh; dl = Bl; off = (c - perMat) * 8; }
    float4 x0 = *(const float4*)(src + off);
    float4 x1 = *(const float4*)(src + off + 4);
    short8 hi, lo;
    conv8(x0, x1, hi, lo);
    *(short8*)(dh + off) = hi;
    *(short8*)(dl + off) = lo;
}

#define GLOAD_LDS16(gp, lp) \
    __builtin_amdgcn_global_load_lds((const __attribute__((address_space(1))) void*)(gp), \
                                     (__attribute__((address_space(3))) void*)(lp), 16, 0, 0)

// ---------------- K1: GEMM energies = A * B^T via split bf16 ----------------
// MODE 0: staged via global_load_lds from presplit bf16 arrays (ws path)
// MODE 1: reg-staged f32 with on-the-fly conversion (fallback, no big ws)
template<int MODE>
__global__ __launch_bounds__(256, 2)
void gemm_kernel(const float* __restrict__ A, const float* __restrict__ B,
                 const short* __restrict__ Ahg, const short* __restrict__ Alg,
                 const short* __restrict__ Bhg, const short* __restrict__ Blg,
                 float* __restrict__ C)
{
    __shared__ __align__(16) short sAh[BM*BK];
    __shared__ __align__(16) short sAl[BM*BK];
    __shared__ __align__(16) short sBh[BM*BK];
    __shared__ __align__(16) short sBl[BM*BK];

    const int tid  = threadIdx.x;
    const int lane = tid & 63, wid = tid >> 6;
    const int bm0 = blockIdx.y * BM, bn0 = blockIdx.x * BN;
    const int wr = wid >> 1, wc = wid & 1;     // 2x2 wave grid, each 64x64
    const int fr = lane & 15, fg = lane >> 4;  // frag row, k-group

    f32x4 acc[4][4] = {};

    for (int kt = 0; kt < K/BK; ++kt){
        if constexpr (MODE == 0){
            // 1024 slots (16B) per array; wave w owns slots [w*256, w*256+256)
            #pragma unroll
            for (int i = 0; i < 4; ++i){
                int bs = wid * 256 + i * 64;        // wave-uniform base slot
                int s  = bs + lane;
                int row = s >> 3, sp = s & 7;
                int col8 = sp ^ (row & 7);          // pre-swizzled global source
                size_t ga = (size_t)(bm0 + row) * K + kt * BK + col8 * 8;
                size_t gb = (size_t)(bn0 + row) * K + kt * BK + col8 * 8;
                GLOAD_LDS16(Ahg + ga, &sAh[bs * 8]);
                GLOAD_LDS16(Alg + ga, &sAl[bs * 8]);
                GLOAD_LDS16(Bhg + gb, &sBh[bs * 8]);
                GLOAD_LDS16(Blg + gb, &sBl[bs * 8]);
            }
        } else {
            #pragma unroll
            for (int i = 0; i < 4; ++i){
                int s = tid + i * 256;
                int row = s >> 3, sp = s & 7;
                int widx = row * BK + ((sp ^ (row & 7)) << 3);
                const float* ga = A + (size_t)(bm0 + row) * K + kt * BK + sp * 8;
                float4 a0 = *(const float4*)ga, a1 = *(const float4*)(ga + 4);
                short8 hi, lo;
                conv8(a0, a1, hi, lo);
                *(short8*)&sAh[widx] = hi;
                *(short8*)&sAl[widx] = lo;
                const float* gb = B + (size_t)(bn0 + row) * K + kt * BK + sp * 8;
                float4 b0 = *(const float4*)gb, b1 = *(const float4*)(gb + 4);
                conv8(b0, b1, hi, lo);
                *(short8*)&sBh[widx] = hi;
                *(short8*)&sBl[widx] = lo;
            }
        }
        __syncthreads();

        #pragma unroll
        for (int ks = 0; ks < 2; ++ks){
            short8 ah[4], al[4], bh[4], bl[4];
            #pragma unroll
            for (int m = 0; m < 4; ++m){
                int row = wr * 64 + m * 16 + fr;
                int idx = row * BK + ((((ks << 2) | fg) ^ (row & 7)) << 3);
                ah[m] = *(const short8*)&sAh[idx];
                al[m] = *(const short8*)&sAl[idx];
            }
            #pragma unroll
            for (int n = 0; n < 4; ++n){
                int row = wc * 64 + n * 16 + fr;
                int idx = row * BK + ((((ks << 2) | fg) ^ (row & 7)) << 3);
                bh[n] = *(const short8*)&sBh[idx];
                bl[n] = *(const short8*)&sBl[idx];
            }
            #pragma unroll
            for (int m = 0; m < 4; ++m){
                #pragma unroll
                for (int n = 0; n < 4; ++n){
                    acc[m][n] = __builtin_amdgcn_mfma_f32_16x16x32_bf16(ah[m], bh[n], acc[m][n], 0, 0, 0);
                    acc[m][n] = __builtin_amdgcn_mfma_f32_16x16x32_bf16(ah[m], bl[n], acc[m][n], 0, 0, 0);
                    acc[m][n] = __builtin_amdgcn_mfma_f32_16x16x32_bf16(al[m], bh[n], acc[m][n], 0, 0, 0);
                }
            }
        }
        __syncthreads();
    }

    // Epilogue: C/D layout col=lane&15, row=(lane>>4)*4+reg
    #pragma unroll
    for (int m = 0; m < 4; ++m){
        int grow_base = bm0 + wr * 64 + m * 16 + fg * 4;
        #pragma unroll
        for (int r = 0; r < 4; ++r){
            float* crow = C + (size_t)(grow_base + r) * N + bn0 + wc * 64 + fr;
            #pragma unroll
            for (int n = 0; n < 4; ++n)
                crow[n * 16] = acc[m][n][r];
        }
    }
}

// ---------------- K2: per-row max & sum-exp ----------------
__global__ __launch_bounds__(256) void row_stats(const float* __restrict__ E, float* __restrict__ stats)
{
    const int row = blockIdx.x;
    const int tid = threadIdx.x;
    const int lane = tid & 63, wid = tid >> 6;
    const float4* rp = (const float4*)(E + (size_t)row * N);
    float4 v[8];
    float mx = -3.4e38f;
    #pragma unroll
    for (int i = 0; i < 8; ++i){
        v[i] = rp[tid + i * 256];
        mx = fmaxf(mx, fmaxf(fmaxf(v[i].x, v[i].y), fmaxf(v[i].z, v[i].w)));
    }
    #pragma unroll
    for (int off = 32; off; off >>= 1) mx = fmaxf(mx, __shfl_xor(mx, off));
    __shared__ float redm[4], reds[4];
    if (lane == 0) redm[wid] = mx;
    __syncthreads();
    mx = fmaxf(fmaxf(redm[0], redm[1]), fmaxf(redm[2], redm[3]));
    float s = 0.f;
    #pragma unroll
    for (int i = 0; i < 8; ++i)
        s += __expf(v[i].x - mx) + __expf(v[i].y - mx) + __expf(v[i].z - mx) + __expf(v[i].w - mx);
    #pragma unroll
    for (int off = 32; off; off >>= 1) s += __shfl_xor(s, off);
    if (lane == 0) reds[wid] = s;
    __syncthreads();
    if (tid == 0){
        stats[2 * row]     = mx;
        stats[2 * row + 1] = reds[0] + reds[1] + reds[2] + reds[3];
    }
}

// ---------------- K3: normalize in place ----------------
__global__ __launch_bounds__(256) void normalize(float* __restrict__ E, const float* __restrict__ stats)
{
    size_t idx = (size_t)blockIdx.x * 256 + threadIdx.x;   // float4 index
    int row = (int)(idx >> 11);                            // 2048 float4 per row
    float m = stats[2 * row];
    float inv = 1.0f / stats[2 * row + 1];
    float4 v = ((const float4*)E)[idx];
    v.x = __expf(v.x - m) * inv;
    v.y = __expf(v.y - m) * inv;
    v.z = __expf(v.z - m) * inv;
    v.w = __expf(v.w - m) * inv;
    ((float4*)E)[idx] = v;
}

extern "C" void kernel_launch(void* const* d_in, const int* in_sizes, int n_in,
                              void* d_out, int out_size, void* d_ws, size_t ws_size,
                              hipStream_t stream)
{
    const float* A = (const float*)d_in[0];  // out_state [M][K]
    const float* B = (const float*)d_in[1];  // history   [N][K]
    float* out = (float*)d_out;

    const size_t elems = (size_t)M * K;                 // 8388608
    const size_t splitBytes = 4 * elems * sizeof(short); // 64 MB
    const size_t statsBytes = (size_t)M * 2 * sizeof(float);

    if (ws_size >= splitBytes + statsBytes){
        short* Ah = (short*)d_ws;
        short* Al = Ah + elems;
        short* Bh = Al + elems;
        short* Bl = Bh + elems;
        float* stats = (float*)(Bl + elems);
        presplit<<<8192, 256, 0, stream>>>(A, B, Ah, Al, Bh, Bl);
        gemm_kernel<0><<<dim3(N/BN, M/BM), 256, 0, stream>>>(A, B, Ah, Al, Bh, Bl, out);
        row_stats<<<M, 256, 0, stream>>>(out, stats);
        normalize<<<(size_t)M * N / 4 / 256, 256, 0, stream>>>(out, stats);
    } else {
        float* stats = (float*)d_ws;
        gemm_kernel<1><<<dim3(N/BN, M/BM), 256, 0, stream>>>(A, B, nullptr, nullptr, nullptr, nullptr, out);
        row_stats<<<M, 256, 0, stream>>>(out, stats);
        normalize<<<(size_t)M * N / 4 / 256, 256, 0, stream>>>(out, stats);
    }
}

// Round 2
// 466.260 us; speedup vs baseline: 1.0333x; 1.0333x over previous
//
#include <hip/hip_runtime.h>
#include <hip/hip_bf16.h>

#define M 8192
#define N 8192
#define K 1024
#define BM 128
#define BN 128
#define BK 64
#define ARR (BM*BK)

typedef __attribute__((ext_vector_type(8))) short short8;
typedef __attribute__((ext_vector_type(4))) float f32x4;

__device__ inline short f2bf(float x){
    __hip_bfloat16 h = __float2bfloat16(x);
    short s; __builtin_memcpy(&s, &h, 2); return s;
}
__device__ inline float bf2f(short s){
    __hip_bfloat16 h; __builtin_memcpy(&h, &s, 2);
    return __bfloat162float(h);
}

__device__ inline void conv8(float4 x0, float4 x1, short8& hi, short8& lo){
    float xs[8] = {x0.x,x0.y,x0.z,x0.w,x1.x,x1.y,x1.z,x1.w};
    #pragma unroll
    for (int j=0;j<8;++j){
        short h = f2bf(xs[j]);
        float r = xs[j] - bf2f(h);
        hi[j] = h; lo[j] = f2bf(r);
    }
}

// ---------------- K0: presplit f32 -> (hi, lo) bf16 ----------------
__global__ __launch_bounds__(256) void presplit(
    const float* __restrict__ A, const float* __restrict__ B,
    short* __restrict__ Ah, short* __restrict__ Al,
    short* __restrict__ Bh, short* __restrict__ Bl)
{
    size_t c = (size_t)blockIdx.x * 256 + threadIdx.x; // chunk of 8 floats
    const float* src; short *dh, *dl; size_t off;
    const size_t perMat = (size_t)M * K / 8; // 1048576
    if (c < perMat){ src = A; dh = Ah; dl = Al; off = c * 8; }
    else           { src = B; dh = Bh; dl = Bl; off = (c - perMat) * 8; }
    float4 x0 = *(const float4*)(src + off);
    float4 x1 = *(const float4*)(src + off + 4);
    short8 hi, lo;
    conv8(x0, x1, hi, lo);
    *(short8*)(dh + off) = hi;
    *(short8*)(dl + off) = lo;
}

#define GLOAD_LDS16(gp, lp) \
    __builtin_amdgcn_global_load_lds((const __attribute__((address_space(1))) void*)(gp), \
                                     (__attribute__((address_space(3))) void*)(lp), 16, 0, 0)

// ---------------- K1: double-buffered split-bf16 GEMM, C = A * B^T ----------------
// 512 threads = 8 waves (2 rows x 4 cols), each wave owns 64x32 of the 128x128 tile.
// LDS: 2 buffers x {Ah, Al, Bh, Bl} x 16 KB = 128 KB -> 1 block/CU, 2 waves/SIMD.
__global__ __launch_bounds__(512, 2)
void gemm_db(const short* __restrict__ Ahg, const short* __restrict__ Alg,
             const short* __restrict__ Bhg, const short* __restrict__ Blg,
             float* __restrict__ C)
{
    __shared__ __align__(16) short lds[2][4][ARR];

    const int tid  = threadIdx.x;
    const int lane = tid & 63, wid = tid >> 6;

    // supertile (4x4 blocks) + bijective XCD chunking: 4096 = 8 XCD x 32 st x 16 pos
    const int hw  = blockIdx.x;
    const int xcd = hw & 7;
    const int ix  = hw >> 3;               // 0..511
    const int gst = xcd * 32 + (ix >> 4);  // global supertile 0..255
    const int pos = ix & 15;
    const int bm0 = ((gst >> 4) * 4 + (pos >> 2)) * BM;
    const int bn0 = ((gst & 15) * 4 + (pos & 3)) * BN;

    const int wr = wid >> 2, wc = wid & 3;     // 2x4 wave grid
    const int fr = lane & 15, fg = lane >> 4;  // frag row, k-group

    f32x4 acc[4][2] = {};

    auto STAGE = [&](int buf, int kt){
        #pragma unroll
        for (int i = 0; i < 2; ++i){
            int bs = wid * 128 + i * 64;        // wave-uniform base slot
            int s  = bs + lane;
            int row = s >> 3, sp = s & 7;
            int col8 = sp ^ (row & 7);          // pre-swizzled global source
            size_t ga = (size_t)(bm0 + row) * K + kt * BK + col8 * 8;
            size_t gb = (size_t)(bn0 + row) * K + kt * BK + col8 * 8;
            GLOAD_LDS16(Ahg + ga, &lds[buf][0][bs * 8]);
            GLOAD_LDS16(Alg + ga, &lds[buf][1][bs * 8]);
            GLOAD_LDS16(Bhg + gb, &lds[buf][2][bs * 8]);
            GLOAD_LDS16(Blg + gb, &lds[buf][3][bs * 8]);
        }
    };

    STAGE(0, 0);
    __syncthreads();
    int cur = 0;

    for (int kt = 0; kt < K/BK; ++kt){
        if (kt + 1 < K/BK) STAGE(cur ^ 1, kt + 1);   // prefetch next tile (in flight across compute)

        const short* sAh = lds[cur][0];
        const short* sAl = lds[cur][1];
        const short* sBh = lds[cur][2];
        const short* sBl = lds[cur][3];

        #pragma unroll
        for (int ks = 0; ks < 2; ++ks){
            short8 ah[4], al[4], bh[2], bl[2];
            #pragma unroll
            for (int m = 0; m < 4; ++m){
                int row = wr * 64 + m * 16 + fr;
                int idx = row * BK + ((((ks << 2) | fg) ^ (row & 7)) << 3);
                ah[m] = *(const short8*)&sAh[idx];
                al[m] = *(const short8*)&sAl[idx];
            }
            #pragma unroll
            for (int n = 0; n < 2; ++n){
                int row = wc * 32 + n * 16 + fr;
                int idx = row * BK + ((((ks << 2) | fg) ^ (row & 7)) << 3);
                bh[n] = *(const short8*)&sBh[idx];
                bl[n] = *(const short8*)&sBl[idx];
            }
            __builtin_amdgcn_s_setprio(1);
            #pragma unroll
            for (int m = 0; m < 4; ++m){
                #pragma unroll
                for (int n = 0; n < 2; ++n){
                    acc[m][n] = __builtin_amdgcn_mfma_f32_16x16x32_bf16(ah[m], bh[n], acc[m][n], 0, 0, 0);
                    acc[m][n] = __builtin_amdgcn_mfma_f32_16x16x32_bf16(ah[m], bl[n], acc[m][n], 0, 0, 0);
                    acc[m][n] = __builtin_amdgcn_mfma_f32_16x16x32_bf16(al[m], bh[n], acc[m][n], 0, 0, 0);
                }
            }
            __builtin_amdgcn_s_setprio(0);
        }
        __syncthreads();   // drains vmcnt(0): stage(t+1) done; everyone done reading buf[cur]
        cur ^= 1;
    }

    // Epilogue: C/D layout col=lane&15, row=(lane>>4)*4+reg
    #pragma unroll
    for (int m = 0; m < 4; ++m){
        int grow = bm0 + wr * 64 + m * 16 + fg * 4;
        #pragma unroll
        for (int r = 0; r < 4; ++r){
            float* crow = C + (size_t)(grow + r) * N + bn0 + wc * 32 + fr;
            crow[0]  = acc[m][0][r];
            crow[16] = acc[m][1][r];
        }
    }
}

// ---------------- K1b: fallback GEMM (no ws): reg-staged f32 with on-the-fly split ----------------
__global__ __launch_bounds__(256, 2)
void gemm_fb(const float* __restrict__ A, const float* __restrict__ B,
             float* __restrict__ C)
{
    __shared__ __align__(16) short sAh[ARR];
    __shared__ __align__(16) short sAl[ARR];
    __shared__ __align__(16) short sBh[ARR];
    __shared__ __align__(16) short sBl[ARR];

    const int tid  = threadIdx.x;
    const int lane = tid & 63, wid = tid >> 6;
    const int bm0 = blockIdx.y * BM, bn0 = blockIdx.x * BN;
    const int wr = wid >> 1, wc = wid & 1;
    const int fr = lane & 15, fg = lane >> 4;

    f32x4 acc[4][4] = {};

    for (int kt = 0; kt < K/BK; ++kt){
        #pragma unroll
        for (int i = 0; i < 4; ++i){
            int s = tid + i * 256;
            int row = s >> 3, sp = s & 7;
            int widx = row * BK + ((sp ^ (row & 7)) << 3);
            const float* ga = A + (size_t)(bm0 + row) * K + kt * BK + sp * 8;
            float4 a0 = *(const float4*)ga, a1 = *(const float4*)(ga + 4);
            short8 hi, lo;
            conv8(a0, a1, hi, lo);
            *(short8*)&sAh[widx] = hi;
            *(short8*)&sAl[widx] = lo;
            const float* gb = B + (size_t)(bn0 + row) * K + kt * BK + sp * 8;
            float4 b0 = *(const float4*)gb, b1 = *(const float4*)(gb + 4);
            conv8(b0, b1, hi, lo);
            *(short8*)&sBh[widx] = hi;
            *(short8*)&sBl[widx] = lo;
        }
        __syncthreads();

        #pragma unroll
        for (int ks = 0; ks < 2; ++ks){
            short8 ah[4], al[4], bh[4], bl[4];
            #pragma unroll
            for (int m = 0; m < 4; ++m){
                int row = wr * 64 + m * 16 + fr;
                int idx = row * BK + ((((ks << 2) | fg) ^ (row & 7)) << 3);
                ah[m] = *(const short8*)&sAh[idx];
                al[m] = *(const short8*)&sAl[idx];
            }
            #pragma unroll
            for (int n = 0; n < 4; ++n){
                int row = wc * 64 + n * 16 + fr;
                int idx = row * BK + ((((ks << 2) | fg) ^ (row & 7)) << 3);
                bh[n] = *(const short8*)&sBh[idx];
                bl[n] = *(const short8*)&sBl[idx];
            }
            #pragma unroll
            for (int m = 0; m < 4; ++m){
                #pragma unroll
                for (int n = 0; n < 4; ++n){
                    acc[m][n] = __builtin_amdgcn_mfma_f32_16x16x32_bf16(ah[m], bh[n], acc[m][n], 0, 0, 0);
                    acc[m][n] = __builtin_amdgcn_mfma_f32_16x16x32_bf16(ah[m], bl[n], acc[m][n], 0, 0, 0);
                    acc[m][n] = __builtin_amdgcn_mfma_f32_16x16x32_bf16(al[m], bh[n], acc[m][n], 0, 0, 0);
                }
            }
        }
        __syncthreads();
    }

    #pragma unroll
    for (int m = 0; m < 4; ++m){
        int grow = bm0 + wr * 64 + m * 16 + fg * 4;
        #pragma unroll
        for (int r = 0; r < 4; ++r){
            float* crow = C + (size_t)(grow + r) * N + bn0 + wc * 64 + fr;
            #pragma unroll
            for (int n = 0; n < 4; ++n)
                crow[n * 16] = acc[m][n][r];
        }
    }
}

// ---------------- K2: fused row softmax (row lives in registers) ----------------
__global__ __launch_bounds__(256) void softmax_fused(float* __restrict__ E)
{
    const int row = blockIdx.x;
    const int tid = threadIdx.x;
    const int lane = tid & 63, wid = tid >> 6;
    float4* rp = (float4*)(E + (size_t)row * N);
    float4 v[8];
    float mx = -3.4e38f;
    #pragma unroll
    for (int i = 0; i < 8; ++i){
        v[i] = rp[tid + i * 256];
        mx = fmaxf(mx, fmaxf(fmaxf(v[i].x, v[i].y), fmaxf(v[i].z, v[i].w)));
    }
    #pragma unroll
    for (int off = 32; off; off >>= 1) mx = fmaxf(mx, __shfl_xor(mx, off));
    __shared__ float redm[4], reds[4];
    if (lane == 0) redm[wid] = mx;
    __syncthreads();
    mx = fmaxf(fmaxf(redm[0], redm[1]), fmaxf(redm[2], redm[3]));
    float s = 0.f;
    #pragma unroll
    for (int i = 0; i < 8; ++i){
        v[i].x = __expf(v[i].x - mx); v[i].y = __expf(v[i].y - mx);
        v[i].z = __expf(v[i].z - mx); v[i].w = __expf(v[i].w - mx);
        s += v[i].x + v[i].y + v[i].z + v[i].w;
    }
    #pragma unroll
    for (int off = 32; off; off >>= 1) s += __shfl_xor(s, off);
    if (lane == 0) reds[wid] = s;
    __syncthreads();
    float inv = 1.0f / (reds[0] + reds[1] + reds[2] + reds[3]);
    #pragma unroll
    for (int i = 0; i < 8; ++i){
        float4 o = v[i];
        o.x *= inv; o.y *= inv; o.z *= inv; o.w *= inv;
        rp[tid + i * 256] = o;
    }
}

extern "C" void kernel_launch(void* const* d_in, const int* in_sizes, int n_in,
                              void* d_out, int out_size, void* d_ws, size_t ws_size,
                              hipStream_t stream)
{
    const float* A = (const float*)d_in[0];  // out_state [M][K]
    const float* B = (const float*)d_in[1];  // history   [N][K]
    float* out = (float*)d_out;

    const size_t elems = (size_t)M * K;                  // 8388608
    const size_t splitBytes = 4 * elems * sizeof(short); // 64 MB

    if (ws_size >= splitBytes){
        short* Ah = (short*)d_ws;
        short* Al = Ah + elems;
        short* Bh = Al + elems;
        short* Bl = Bh + elems;
        presplit<<<8192, 256, 0, stream>>>(A, B, Ah, Al, Bh, Bl);
        gemm_db<<<(M/BM)*(N/BN), 512, 0, stream>>>(Ah, Al, Bh, Bl, out);
    } else {
        gemm_fb<<<dim3(N/BN, M/BM), 256, 0, stream>>>(A, B, out);
    }
    softmax_fused<<<M, 256, 0, stream>>>(out);
}

// Round 3
// 453.786 us; speedup vs baseline: 1.0617x; 1.0275x over previous
//
#include <hip/hip_runtime.h>
#include <hip/hip_bf16.h>

#define M 8192
#define N 8192
#define K 1024
#define BM 256
#define BN 256
#define BK 32
#define KT (K/BK)   // 32 k-steps

typedef __attribute__((ext_vector_type(8))) short short8;
typedef __attribute__((ext_vector_type(4))) float f32x4;

__device__ inline short f2bf(float x){
    __hip_bfloat16 h = __float2bfloat16(x);
    short s; __builtin_memcpy(&s, &h, 2); return s;
}
__device__ inline float bf2f(short s){
    __hip_bfloat16 h; __builtin_memcpy(&h, &s, 2);
    return __bfloat162float(h);
}

__device__ inline void conv8(float4 x0, float4 x1, short8& hi, short8& lo){
    float xs[8] = {x0.x,x0.y,x0.z,x0.w,x1.x,x1.y,x1.z,x1.w};
    #pragma unroll
    for (int j=0;j<8;++j){
        short h = f2bf(xs[j]);
        float r = xs[j] - bf2f(h);
        hi[j] = h; lo[j] = f2bf(r);
    }
}

#define GLOAD_LDS16(gp, lp) \
    __builtin_amdgcn_global_load_lds((const __attribute__((address_space(1))) void*)(gp), \
                                     (__attribute__((address_space(3))) void*)(lp), 16, 0, 0)

// ---------------- K0: presplit f32 -> (hi, lo) bf16 in TRANSPOSED [k8][row] layout ----
// Output granule g = k8*M + row holds 8 bf16 (16B). Within a 512-thread block,
// threads t, t+128, t+256, t+384 write rows r..r+3 of the same k8 -> full 64B lines.
__global__ __launch_bounds__(512) void presplit_t(
    const float* __restrict__ A, const float* __restrict__ B,
    short* __restrict__ Aht, short* __restrict__ Alt,
    short* __restrict__ Bht, short* __restrict__ Blt)
{
    size_t c = (size_t)blockIdx.x * 512 + threadIdx.x;
    const float* src; short *dh, *dl;
    const size_t perMat = (size_t)M * (K/8); // 1048576 granules per matrix
    if (c < perMat){ src = A; dh = Aht; dl = Alt; }
    else { c -= perMat; src = B; dh = Bht; dl = Blt; }
    int row = (int)(c >> 7);      // / (K/8)
    int k8  = (int)(c & 127);
    const float* p = src + (size_t)row * K + k8 * 8;
    float4 x0 = *(const float4*)p;
    float4 x1 = *(const float4*)(p + 4);
    short8 hi, lo; conv8(x0, x1, hi, lo);
    size_t o = ((size_t)k8 * M + row) * 8;
    *(short8*)(dh + o) = hi;
    *(short8*)(dl + o) = lo;
}

// ---------------- K1: split-bf16 GEMM C = A * B^T, 256x256 tile, 8 waves of 128x64 ----
// LDS: lds[buf][arr][slot][row][8] ; arr: 0=Ah 1=Al 2=Bh 3=Bl ; slot = k-group (lane>>4).
// Staging is linear (global_load_lds), sources coalesced (transposed global layout),
// fragment ds_read_b128 is contiguous per 16-lane group -> conflict-free, no swizzle.
__global__ __launch_bounds__(512, 2)
void gemm_t(const short* __restrict__ Aht, const short* __restrict__ Alt,
            const short* __restrict__ Bht, const short* __restrict__ Blt,
            float* __restrict__ C)
{
    __shared__ __align__(16) short lds[2][4][4][BM][8];   // 128 KB

    const int tid  = threadIdx.x;
    const int lane = tid & 63, wid = tid >> 6;

    // bijective XCD chunking: 1024 blocks = 8 xcd x 128; per chunk: 4 block-rows x 32 cols
    const int xcd = blockIdx.x & 7;
    const int gid = xcd * 128 + (blockIdx.x >> 3);
    const int bm0 = (gid >> 5) * BM;
    const int bn0 = (gid & 31) * BN;

    const int wr = wid >> 2, wc = wid & 3;      // 2x4 wave grid; wave tile 128x64
    const int fr = lane & 15, fg = lane >> 4;   // frag row, k-group (= slot)

    // staging role: wave pair (wid>>1) owns one array; wid&1 selects slot half
    const int arr = wid >> 1;
    const short* gp = (arr == 0) ? Aht : (arr == 1) ? Alt : (arr == 2) ? Bht : Blt;
    const int   gb  = (arr < 2) ? bm0 : bn0;
    const int sbase = (wid & 1) * 2;

    f32x4 acc[8][4] = {};

    auto STAGE = [&](int buf, int kt){
        #pragma unroll
        for (int i = 0; i < 8; ++i){
            int s  = sbase + (i >> 2);
            int rb = i & 3;
            const short* src = gp + (((size_t)(kt * 4 + s)) * M + gb + rb * 64 + lane) * 8;
            GLOAD_LDS16(src, &lds[buf][arr][s][rb * 64][0]);   // dest: uniform base + lane*16
        }
    };

    STAGE(0, 0);
    __syncthreads();
    int cur = 0;

    for (int kt = 0; kt < KT; ++kt){
        if (kt + 1 < KT) STAGE(cur ^ 1, kt + 1);   // prefetch: in flight across MFMA phase

        short8 ah[8], al[8], bh[4], bl[4];
        #pragma unroll
        for (int m = 0; m < 8; ++m){
            int row = wr * 128 + m * 16 + fr;
            ah[m] = *(const short8*)&lds[cur][0][fg][row][0];
            al[m] = *(const short8*)&lds[cur][1][fg][row][0];
        }
        #pragma unroll
        for (int n = 0; n < 4; ++n){
            int row = wc * 64 + n * 16 + fr;
            bh[n] = *(const short8*)&lds[cur][2][fg][row][0];
            bl[n] = *(const short8*)&lds[cur][3][fg][row][0];
        }

        __builtin_amdgcn_s_setprio(1);
        #pragma unroll
        for (int m = 0; m < 8; ++m){
            #pragma unroll
            for (int n = 0; n < 4; ++n){
                acc[m][n] = __builtin_amdgcn_mfma_f32_16x16x32_bf16(ah[m], bh[n], acc[m][n], 0, 0, 0);
                acc[m][n] = __builtin_amdgcn_mfma_f32_16x16x32_bf16(ah[m], bl[n], acc[m][n], 0, 0, 0);
                acc[m][n] = __builtin_amdgcn_mfma_f32_16x16x32_bf16(al[m], bh[n], acc[m][n], 0, 0, 0);
            }
        }
        __builtin_amdgcn_s_setprio(0);

        __syncthreads();   // drains vmcnt(0): prefetch landed; all waves done reading cur
        cur ^= 1;
    }

    // Epilogue: C/D layout col=lane&15, row=(lane>>4)*4+reg  (verified in rounds 0-2)
    #pragma unroll
    for (int m = 0; m < 8; ++m){
        int grow = bm0 + wr * 128 + m * 16 + fg * 4;
        #pragma unroll
        for (int r = 0; r < 4; ++r){
            float* crow = C + (size_t)(grow + r) * N + bn0 + wc * 64 + fr;
            #pragma unroll
            for (int n = 0; n < 4; ++n)
                crow[n * 16] = acc[m][n][r];
        }
    }
}

// ---------------- K1b: fallback GEMM (no ws): reg-staged f32 on-the-fly split ----------
#define FBM 128
#define FBN 128
#define FBK 64
#define FARR (FBM*FBK)
__global__ __launch_bounds__(256, 2)
void gemm_fb(const float* __restrict__ A, const float* __restrict__ B,
             float* __restrict__ C)
{
    __shared__ __align__(16) short sAh[FARR];
    __shared__ __align__(16) short sAl[FARR];
    __shared__ __align__(16) short sBh[FARR];
    __shared__ __align__(16) short sBl[FARR];

    const int tid  = threadIdx.x;
    const int lane = tid & 63, wid = tid >> 6;
    const int bm0 = blockIdx.y * FBM, bn0 = blockIdx.x * FBN;
    const int wr = wid >> 1, wc = wid & 1;
    const int fr = lane & 15, fg = lane >> 4;

    f32x4 acc[4][4] = {};

    for (int kt = 0; kt < K/FBK; ++kt){
        #pragma unroll
        for (int i = 0; i < 4; ++i){
            int s = tid + i * 256;
            int row = s >> 3, sp = s & 7;
            int widx = row * FBK + ((sp ^ (row & 7)) << 3);
            const float* ga = A + (size_t)(bm0 + row) * K + kt * FBK + sp * 8;
            float4 a0 = *(const float4*)ga, a1 = *(const float4*)(ga + 4);
            short8 hi, lo;
            conv8(a0, a1, hi, lo);
            *(short8*)&sAh[widx] = hi;
            *(short8*)&sAl[widx] = lo;
            const float* gbp = B + (size_t)(bn0 + row) * K + kt * FBK + sp * 8;
            float4 b0 = *(const float4*)gbp, b1 = *(const float4*)(gbp + 4);
            conv8(b0, b1, hi, lo);
            *(short8*)&sBh[widx] = hi;
            *(short8*)&sBl[widx] = lo;
        }
        __syncthreads();

        #pragma unroll
        for (int ks = 0; ks < 2; ++ks){
            short8 ah[4], al[4], bh[4], bl[4];
            #pragma unroll
            for (int m = 0; m < 4; ++m){
                int row = wr * 64 + m * 16 + fr;
                int idx = row * FBK + ((((ks << 2) | fg) ^ (row & 7)) << 3);
                ah[m] = *(const short8*)&sAh[idx];
                al[m] = *(const short8*)&sAl[idx];
            }
            #pragma unroll
            for (int n = 0; n < 4; ++n){
                int row = wc * 64 + n * 16 + fr;
                int idx = row * FBK + ((((ks << 2) | fg) ^ (row & 7)) << 3);
                bh[n] = *(const short8*)&sBh[idx];
                bl[n] = *(const short8*)&sBl[idx];
            }
            #pragma unroll
            for (int m = 0; m < 4; ++m){
                #pragma unroll
                for (int n = 0; n < 4; ++n){
                    acc[m][n] = __builtin_amdgcn_mfma_f32_16x16x32_bf16(ah[m], bh[n], acc[m][n], 0, 0, 0);
                    acc[m][n] = __builtin_amdgcn_mfma_f32_16x16x32_bf16(ah[m], bl[n], acc[m][n], 0, 0, 0);
                    acc[m][n] = __builtin_amdgcn_mfma_f32_16x16x32_bf16(al[m], bh[n], acc[m][n], 0, 0, 0);
                }
            }
        }
        __syncthreads();
    }

    #pragma unroll
    for (int m = 0; m < 4; ++m){
        int grow = bm0 + wr * 64 + m * 16 + fg * 4;
        #pragma unroll
        for (int r = 0; r < 4; ++r){
            float* crow = C + (size_t)(grow + r) * N + bn0 + wc * 64 + fr;
            #pragma unroll
            for (int n = 0; n < 4; ++n)
                crow[n * 16] = acc[m][n][r];
        }
    }
}

// ---------------- K2: fused row softmax (row lives in registers) ----------------
__global__ __launch_bounds__(256) void softmax_fused(float* __restrict__ E)
{
    const int row = blockIdx.x;
    const int tid = threadIdx.x;
    const int lane = tid & 63, wid = tid >> 6;
    float4* rp = (float4*)(E + (size_t)row * N);
    float4 v[8];
    float mx = -3.4e38f;
    #pragma unroll
    for (int i = 0; i < 8; ++i){
        v[i] = rp[tid + i * 256];
        mx = fmaxf(mx, fmaxf(fmaxf(v[i].x, v[i].y), fmaxf(v[i].z, v[i].w)));
    }
    #pragma unroll
    for (int off = 32; off; off >>= 1) mx = fmaxf(mx, __shfl_xor(mx, off));
    __shared__ float redm[4], reds[4];
    if (lane == 0) redm[wid] = mx;
    __syncthreads();
    mx = fmaxf(fmaxf(redm[0], redm[1]), fmaxf(redm[2], redm[3]));
    float s = 0.f;
    #pragma unroll
    for (int i = 0; i < 8; ++i){
        v[i].x = __expf(v[i].x - mx); v[i].y = __expf(v[i].y - mx);
        v[i].z = __expf(v[i].z - mx); v[i].w = __expf(v[i].w - mx);
        s += v[i].x + v[i].y + v[i].z + v[i].w;
    }
    #pragma unroll
    for (int off = 32; off; off >>= 1) s += __shfl_xor(s, off);
    if (lane == 0) reds[wid] = s;
    __syncthreads();
    float inv = 1.0f / (reds[0] + reds[1] + reds[2] + reds[3]);
    #pragma unroll
    for (int i = 0; i < 8; ++i){
        float4 o = v[i];
        o.x *= inv; o.y *= inv; o.z *= inv; o.w *= inv;
        rp[tid + i * 256] = o;
    }
}

extern "C" void kernel_launch(void* const* d_in, const int* in_sizes, int n_in,
                              void* d_out, int out_size, void* d_ws, size_t ws_size,
                              hipStream_t stream)
{
    const float* A = (const float*)d_in[0];  // out_state [M][K]
    const float* B = (const float*)d_in[1];  // history   [N][K]
    float* out = (float*)d_out;

    const size_t elems = (size_t)M * K;                  // 8388608
    const size_t splitBytes = 4 * elems * sizeof(short); // 64 MB

    if (ws_size >= splitBytes){
        short* Aht = (short*)d_ws;
        short* Alt = Aht + elems;
        short* Bht = Alt + elems;
        short* Blt = Bht + elems;
        presplit_t<<<4096, 512, 0, stream>>>(A, B, Aht, Alt, Bht, Blt);
        gemm_t<<<(M/BM)*(N/BN), 512, 0, stream>>>(Aht, Alt, Bht, Blt, out);
    } else {
        gemm_fb<<<dim3(N/FBN, M/FBM), 256, 0, stream>>>(A, B, out);
    }
    softmax_fused<<<M, 256, 0, stream>>>(out);
}